// Round 8
// baseline (1111.675 us; speedup 1.0000x reference)
//
#include <hip/hip_runtime.h>

#define D_IN 2312
#define HID  800
#define NCLS 10
#define BATCH 128
#define TSTEPS 300
#define WIN  50

#define MT 64                              // block tile rows (2 waves x 32)
#define NT 32
#define BKK 16
#define NSLAB 145                          // ceil(2312/16), last slab rem=8
#define NTM 100                            // 6400/64
#define NTN 25                             // 800/32, exact
#define GEMM_BLOCKS (NTM * NTN)            // 2500 two-wave tiles
#define BLK 128
#define RPASTE 1920                        // paste blocks appended to recur launch
#define TOTQ (BATCH * D_IN * (TSTEPS / 4)) // 22,195,200 float4s of X

// async global->LDS (4B/lane): LDS dest is wave-uniform base + lane*4,
// global src is per-lane. Removes the VGPR round-trip + LDS-write issue.
__device__ __forceinline__ void async_copy4(const float* g, float* l) {
  __builtin_amdgcn_global_load_lds(
      (const __attribute__((address_space(1))) unsigned int*)g,
      (__attribute__((address_space(3))) unsigned int*)l, 4, 0, 0);
}

// ---------------------------------------------------------------------------
// GEMM-only kernel (paste moved to the recur dispatch, where it overlaps the
// latency-bound recurrence instead of serially stealing GEMM time).
// Round-1 micro-kernel (proven 48 VGPR, no spill) with:
//   * A staged by global_load_lds DMA (8 instrs/wave/slab, no regs/writes)
//   * double-buffered As[2]/Bs[2] -> ONE barrier per slab (was 2)
//   * mt-major order (FETCH 834->580 MB proven in R7)
// Per-output k-accumulation strictly sequential fmaf -> bit-identical P.
// Lane l <-> A-row m0+l: DMA dest As[buf][kr][0]+lane*4 matches compute's
// As[kk][m-index] layout exactly. Partial last slab: DMA valid k-rows, LDS
// rows >= rem zero-filled (FMAs add exact 0s, same as old zero-fill).
// ---------------------------------------------------------------------------
__global__ __launch_bounds__(BLK) void gemm_kernel(
    const float* __restrict__ inp,   // [B][D_IN][WIN]
    const float* __restrict__ W1,    // [HID][D_IN]
    float*       __restrict__ P)     // [6400][HID]
{
  __shared__ float As[2][BKK][MT];       // 8 KB, unpadded (DMA rows linear)
  __shared__ float Bs[2][BKK][NT + 4];   // 4.5 KB, padded (reg-staged)

  int t  = threadIdx.x;
  int bx = blockIdx.x;

  int mt = bx / NTN;                 // 25 consecutive blocks share m-tile
  int nt = bx - mt * NTN;
  int m0 = mt * MT, n0 = nt * NT;

  // A: lane l covers row m0+l (s-contiguous within each batch's 50 rows)
  int am = t & 63;
  int ah = t >> 6;                   // wave id: wave ah stages k-rows ah*8..+7
  int r  = m0 + am;
  int bb = r / 50, ss = r - bb * 50;
  const float* aptr = inp + (size_t)bb * (D_IN * WIN) + ss;   // + k*WIN

  // B staging: 32 n x 16 k by 128 threads (4 each), coalesced along k
  int bn = t >> 4;                   // 0..7
  int bk = t & 15;                   // 0..15

  int l  = t & 63;
  int lm = l & 7;                    // m micro-group
  int ln = l >> 3;                   // n micro-group
  int tm = ah * 32 + lm * 4;         // wave ah owns rows [ah*32, ah*32+32)
  int tn = ln * 4;

  // ---- prologue: stage slab 0 into buf 0 ----
#pragma unroll
  for (int q = 0; q < 8; ++q) {
    int kr = ah * 8 + q;
    async_copy4(aptr + (size_t)kr * WIN, &As[0][kr][0]);
  }
  float bN[4];
#pragma unroll
  for (int p = 0; p < 4; ++p)
    bN[p] = W1[(size_t)(n0 + bn + 8 * p) * D_IN + bk];
#pragma unroll
  for (int p = 0; p < 4; ++p) Bs[0][bk][bn + 8 * p] = bN[p];
  __syncthreads();   // compiler drains vmcnt before s_barrier -> slab 0 ready

  float acc[4][4] = {};

  for (int s = 0; s < NSLAB; ++s) {
    int cur = s & 1, nxt = cur ^ 1;
    int k0n = (s + 1) * BKK;
    bool stage = (k0n < D_IN);

    if (stage) {
      int rem = D_IN - k0n;
      if (rem >= BKK) {
        // full next slab: DMA A, load B to regs (hot path, 143/144 stages)
#pragma unroll
        for (int q = 0; q < 8; ++q) {
          int kr = ah * 8 + q;
          async_copy4(aptr + (size_t)(k0n + kr) * WIN, &As[nxt][kr][0]);
        }
#pragma unroll
        for (int p = 0; p < 4; ++p)
          bN[p] = W1[(size_t)(n0 + bn + 8 * p) * D_IN + k0n + bk];
      } else {
        // partial: DMA valid k-rows, zero-fill the rest (exact 0 adds)
#pragma unroll
        for (int q = 0; q < 8; ++q) {
          int kr = ah * 8 + q;
          if (kr < rem)
            async_copy4(aptr + (size_t)(k0n + kr) * WIN, &As[nxt][kr][0]);
          else
            As[nxt][kr][am] = 0.f;
        }
#pragma unroll
        for (int p = 0; p < 4; ++p) {
          int kg = k0n + bk;
          bN[p] = (kg < D_IN) ? W1[(size_t)(n0 + bn + 8 * p) * D_IN + kg] : 0.f;
        }
      }
    }

    // compute slab s from buf cur (DMA to nxt flies under these 256 FMAs)
#pragma unroll
    for (int kk = 0; kk < BKK; ++kk) {
      float4 A0 = *(const float4*)&As[cur][kk][tm];
      float4 B0 = *(const float4*)&Bs[cur][kk][tn];
      float av[4] = {A0.x, A0.y, A0.z, A0.w};
      float bv[4] = {B0.x, B0.y, B0.z, B0.w};
#pragma unroll
      for (int i = 0; i < 4; ++i)
#pragma unroll
        for (int j = 0; j < 4; ++j)
          acc[i][j] += av[i] * bv[j];
    }

    if (stage) {
#pragma unroll
      for (int p = 0; p < 4; ++p) Bs[nxt][bk][bn + 8 * p] = bN[p];
    }
    if (s + 1 < NSLAB) __syncthreads();   // one barrier per slab
  }

#pragma unroll
  for (int i = 0; i < 4; ++i) {
    int row = m0 + tm + i;
    *(float4*)&P[(size_t)row * HID + n0 + tn] =
        make_float4(acc[i][0], acc[i][1], acc[i][2], acc[i][3]);
  }
}

// ---------------------------------------------------------------------------
// DPP full-wave sum (proven round 6): VALU-speed cross-lane, no LDS pipe.
// ---------------------------------------------------------------------------
template <int CTRL>
__device__ __forceinline__ float dpp_add(float s) {
  return s + __int_as_float(__builtin_amdgcn_update_dpp(
      0, __float_as_int(s), CTRL, 0xf, 0xf, true));
}
__device__ __forceinline__ float wave_sum(float s) {
  s = dpp_add<0x111>(s);   // row_shr:1
  s = dpp_add<0x112>(s);   // row_shr:2
  s = dpp_add<0x114>(s);   // row_shr:4
  s = dpp_add<0x118>(s);   // row_shr:8   -> lane15 of each row = row sum
  s = dpp_add<0x142>(s);   // row_bcast:15 -> lane31 = r0+r1, lane63 = r2+r3
  s = dpp_add<0x143>(s);   // row_bcast:31 -> lane63 = total
  return __int_as_float(__builtin_amdgcn_readlane(__float_as_int(s), 63));
}

// ---------------------------------------------------------------------------
// Recurrence v7 — v6 compute path UNCHANGED (W2/Wc/b1 in registers, DPP
// reductions, 1-step P prefetch). NEW: paste runs as extra blocks of THIS
// launch (blockIdx >= BATCH), overlapping the ~426 MB X-write stream with
// the latency-bound recurrence on otherwise-idle CUs. recur blocks take
// blockIdx 0..127 so they dispatch first.
// ---------------------------------------------------------------------------
__global__ __launch_bounds__(64, 1) void recur_kernel(
    const float* __restrict__ P,    // [6400][HID]
    const float* __restrict__ W2,   // [NCLS][HID]
    const float* __restrict__ b2,   // [NCLS]
    const float* __restrict__ Wc,   // [HID+4]
    const float* __restrict__ bc,   // [1]
    const float* __restrict__ b1,   // [HID]
    const int*   __restrict__ idx,  // [B]
    float*       __restrict__ out,  // [B][NCLS]
    const float* __restrict__ inp,  // [B][D_IN][WIN]  (paste)
    float*       __restrict__ outX) // [B][D_IN][T]    (paste)
{
  int L = threadIdx.x;
  int b = blockIdx.x;

  if (b >= BATCH) {
    // ---- paste path: X = zeros with input window pasted at idx[b] ----
    int tid = (b - BATCH) * 64 + L;
    const int stride = RPASTE * 64;
    for (int i = tid; i < TOTQ; i += stride) {
      int q  = i % 75;
      int rd = i / 75;
      int bb = rd / D_IN;
      int d  = rd - bb * D_IN;
      int ib = idx[bb];
      const float* ip = inp + (size_t)bb * (D_IN * WIN) + (size_t)d * WIN;
      int t0 = q * 4;
      float v[4];
#pragma unroll
      for (int e = 0; e < 4; ++e) {
        unsigned w = (unsigned)(t0 + e - ib);
        v[e] = (w < (unsigned)WIN) ? ip[w] : 0.f;
      }
      *(float4*)&outX[(size_t)rd * TSTEPS + t0] = make_float4(v[0], v[1], v[2], v[3]);
    }
    return;
  }

  int myidx = idx[b];
  const float* Pb = P + (size_t)b * WIN * HID;

  float m[13], b1r[13], wcr[13];
  float w2r[NCLS][13];
  unsigned smask = 0;
#pragma unroll
  for (int rr = 0; rr < 13; ++rr) {
    int j = L + 64 * rr;
    bool ok = (j < HID);
    m[rr]   = 0.f;
    b1r[rr] = ok ? b1[j] : 0.f;
    wcr[rr] = ok ? Wc[j] : 0.f;
#pragma unroll
    for (int c = 0; c < NCLS; ++c)
      w2r[c][rr] = ok ? W2[c * HID + j] : 0.f;
  }

  float cm = 0.f, cs = 0.f, bgt = 1.f;
  float bc0 = bc[0];
  float wf0 = Wc[HID], wf1 = Wc[HID + 1], wf2 = Wc[HID + 2], wf3 = Wc[HID + 3];

  float h2m[10], h2s[10], sum2[10], b2r[10];
#pragma unroll
  for (int c = 0; c < NCLS; ++c) { h2m[c] = 0.f; h2s[c] = 0.f; sum2[c] = 0.f; b2r[c] = b2[c]; }

  // prefetch P row for step 0
  float cur[13];
  {
    unsigned w0 = (unsigned)(0 - myidx);
    if (w0 < (unsigned)WIN) {
      const float* Pr = Pb + (size_t)w0 * HID;
#pragma unroll
      for (int rr = 0; rr < 13; ++rr) {
        int j = L + 64 * rr;
        cur[rr] = (j < HID) ? Pr[j] : 0.f;
      }
    } else {
#pragma unroll
      for (int rr = 0; rr < 13; ++rr) cur[rr] = 0.f;
    }
  }

  for (int step = 0; step < TSTEPS; ++step) {
    float gate = (step == 0) ? 1.f : cs;

    // unconditional prefetch of next step's P row (independent of this
    // step's chain; gating is applied at use as *gate, exact for {0,1})
    float nxt[13];
    {
      unsigned wn = (unsigned)(step + 1 - myidx);
      if (wn < (unsigned)WIN) {
        const float* Pr = Pb + (size_t)wn * HID;
#pragma unroll
        for (int rr = 0; rr < 13; ++rr) {
          int j = L + 64 * rr;
          nxt[rr] = (j < HID) ? Pr[j] : 0.f;
        }
      } else {
#pragma unroll
        for (int rr = 0; rr < 13; ++rr) nxt[rr] = 0.f;
      }
    }

    unsigned nmask = 0;
#pragma unroll
    for (int rr = 0; rr < 13; ++rr) {
      float mprev = ((smask >> rr) & 1u) ? 0.f : m[rr] * 0.1f;
      float mv = mprev + cur[rr] * gate + b1r[rr];
      m[rr] = mv;
      nmask |= (mv > 0.5f) ? (1u << rr) : 0u;
    }
    smask = nmask;

    unsigned long long ball = __ballot(smask != 0u);

    float ctrl = 0.f;
    float dot[10];
#pragma unroll
    for (int c = 0; c < NCLS; ++c) dot[c] = 0.f;

    if (ball) {
      // ctrl dot: branchless FMA over own units, DPP wave reduce
      float cacc = 0.f;
#pragma unroll
      for (int rr = 0; rr < 13; ++rr) {
        float f = (float)((smask >> rr) & 1u);
        cacc = fmaf(f, wcr[rr], cacc);
      }
      ctrl = wave_sum(cacc);

      // h2 dots: per-lane partials over own 13 units (all-register), then
      // DPP wave reduce x10
#pragma unroll
      for (int rr = 0; rr < 13; ++rr) {
        float f = (float)((smask >> rr) & 1u);
#pragma unroll
        for (int c = 0; c < NCLS; ++c)
          dot[c] = fmaf(f, w2r[c][rr], dot[c]);
      }
#pragma unroll
      for (int c = 0; c < NCLS; ++c) dot[c] = wave_sum(dot[c]);
    }

    // ctrl neuron + budget (uses prev-step cs, then updates it)
    bgt += (cs == 1.f) ? 1.f : 0.f;
    float fq = wf0;
    if ((step & 1) == 0)   fq += wf1;
    if (step % 10 == 0)    fq += wf2;
    if (step % 100 == 0)   fq += wf3;
    float cv = (cs != 0.f ? 0.f : cm * 0.1f) + ctrl + fq + bc0;
    cm = cv;
    cs = (cv > 0.5f) ? 1.f : 0.f;

    // h2 membrane update every step (dot==0 on silent steps)
#pragma unroll
    for (int c = 0; c < NCLS; ++c) {
      float v = (h2s[c] != 0.f ? 0.f : h2m[c] * 0.1f) + dot[c] + b2r[c];
      h2m[c] = v;
      h2s[c] = (v > 0.5f) ? 1.f : 0.f;
      sum2[c] += h2s[c];
    }

#pragma unroll
    for (int rr = 0; rr < 13; ++rr) cur[rr] = nxt[rr];
  }

  if (L == 0) {
#pragma unroll
    for (int c = 0; c < NCLS; ++c) out[b * NCLS + c] = sum2[c] / bgt;
  }
}

// ---------------------------------------------------------------------------
extern "C" void kernel_launch(void* const* d_in, const int* in_sizes, int n_in,
                              void* d_out, int out_size, void* d_ws, size_t ws_size,
                              hipStream_t stream) {
  const float* inp = (const float*)d_in[0];
  const int*   idx = (const int*)d_in[2];
  const float* W1  = (const float*)d_in[3];
  const float* b1  = (const float*)d_in[4];
  const float* W2  = (const float*)d_in[5];
  const float* b2  = (const float*)d_in[6];
  const float* Wc  = (const float*)d_in[7];
  const float* bc  = (const float*)d_in[8];

  float* out = (float*)d_out;   // [0,1280): rate ; then X
  float* P   = (float*)d_ws;    // [6400][800] fp32 = 20.48 MB

  gemm_kernel<<<GEMM_BLOCKS, BLK, 0, stream>>>(inp, W1, P);

  recur_kernel<<<BATCH + RPASTE, 64, 0, stream>>>(
      P, W2, b2, Wc, bc, b1, idx, out, inp, out + BATCH * NCLS);
}

// Round 9
// 1031.582 us; speedup vs baseline: 1.0776x; 1.0776x over previous
//
#include <hip/hip_runtime.h>

#define D_IN 2312
#define HID  800
#define NCLS 10
#define BATCH 128
#define TSTEPS 300
#define WIN  50

#define MT 64                              // block tile rows (2 waves x 32)
#define NT 32
#define BKK 16
#define NTM 100                            // 6400/64
#define NTN 25                             // 800/32, exact
#define GEMM_BLOCKS (NTM * NTN)            // 2500 two-wave tiles
#define BLK 128
#define RPASTE 1920                        // paste blocks appended to recur launch
#define TOTQ (BATCH * D_IN * (TSTEPS / 4)) // 22,195,200 float4s of X

// ---------------------------------------------------------------------------
// GEMM-only kernel — EXACT R7 fused structure minus the paste branch (paste
// now overlaps the recur launch, proven free in R8). Register-staged
// prefetch, 2 barriers/slab, 48 VGPR no-spill, mt-major order (25 consecutive
// blocks share one A m-tile; FETCH 834->580 MB proven R7). R8's DMA dbuf
// regressed (occupancy 25%, vmcnt(0) drain per barrier with no TLP) - reverted.
// Per-output k-accumulation strictly sequential fmaf -> bit-identical P.
// ---------------------------------------------------------------------------
__global__ __launch_bounds__(BLK) void gemm_kernel(
    const float* __restrict__ inp,   // [B][D_IN][WIN]
    const float* __restrict__ W1,    // [HID][D_IN]
    float*       __restrict__ P)     // [6400][HID]
{
  __shared__ float As[BKK][MT];       // 4 KB
  __shared__ float Bs[BKK][NT + 4];   // 2.25 KB

  int t  = threadIdx.x;
  int bx = blockIdx.x;

  int mt = bx / NTN;                 // 25 consecutive blocks share m-tile (A in L2)
  int nt = bx - mt * NTN;
  int m0 = mt * MT, n0 = nt * NT;

  // A staging: 64 rows x 16 k staged by 128 threads (8 k's each),
  // coalesced along m (s-contiguous)
  int am = t & 63;
  int ah = t >> 6;                   // 0..1 -> k-half (== wave id)
  int r  = m0 + am;
  int bb = r / 50, ss = r - bb * 50;
  const float* aptr = inp + (size_t)bb * (D_IN * WIN) + ss;   // + k*WIN

  // B staging: 32 n x 16 k by 128 threads (4 each), coalesced along k
  int bn = t >> 4;                   // 0..7
  int bk = t & 15;                   // 0..15

  int l  = t & 63;
  int lm = l & 7;                    // m micro-group
  int ln = l >> 3;                   // n micro-group
  int tm = ah * 32 + lm * 4;         // wave ah owns rows [ah*32, ah*32+32)
  int tn = ln * 4;

  float aN[8], bN[4];
#pragma unroll
  for (int q = 0; q < 8; ++q) aN[q] = aptr[(ah * 8 + q) * WIN];
#pragma unroll
  for (int p = 0; p < 4; ++p)
    bN[p] = W1[(size_t)(n0 + bn + 8 * p) * D_IN + bk];

  float acc[4][4] = {};

  for (int k0 = 0; k0 < D_IN; k0 += BKK) {   // 145 slabs, last partial
#pragma unroll
    for (int q = 0; q < 8; ++q) As[ah * 8 + q][am] = aN[q];
#pragma unroll
    for (int p = 0; p < 4; ++p) Bs[bk][bn + 8 * p] = bN[p];
    __syncthreads();

    int kn0 = k0 + BKK;
    if (kn0 + BKK <= D_IN) {
      // next slab fully in range: guard-free prefetch (hot path, 143/145)
#pragma unroll
      for (int q = 0; q < 8; ++q) aN[q] = aptr[(kn0 + ah * 8 + q) * WIN];
#pragma unroll
      for (int p = 0; p < 4; ++p)
        bN[p] = W1[(size_t)(n0 + bn + 8 * p) * D_IN + kn0 + bk];
    } else if (kn0 < D_IN) {
      // next slab partial: guarded, zero-fill (adds exact 0s to acc)
#pragma unroll
      for (int q = 0; q < 8; ++q) {
        int kk = kn0 + ah * 8 + q;
        aN[q] = (kk < D_IN) ? aptr[kk * WIN] : 0.f;
      }
#pragma unroll
      for (int p = 0; p < 4; ++p) {
        int kk = kn0 + bk;
        bN[p] = (kk < D_IN) ? W1[(size_t)(n0 + bn + 8 * p) * D_IN + kk] : 0.f;
      }
    }

#pragma unroll
    for (int kk = 0; kk < BKK; ++kk) {
      float4 A0 = *(const float4*)&As[kk][tm];
      float4 B0 = *(const float4*)&Bs[kk][tn];
      float av[4] = {A0.x, A0.y, A0.z, A0.w};
      float bv[4] = {B0.x, B0.y, B0.z, B0.w};
#pragma unroll
      for (int i = 0; i < 4; ++i)
#pragma unroll
        for (int j = 0; j < 4; ++j)
          acc[i][j] += av[i] * bv[j];
    }
    __syncthreads();
  }

#pragma unroll
  for (int i = 0; i < 4; ++i) {
    int row = m0 + tm + i;
    *(float4*)&P[(size_t)row * HID + n0 + tn] =
        make_float4(acc[i][0], acc[i][1], acc[i][2], acc[i][3]);
  }
}

// ---------------------------------------------------------------------------
// DPP full-wave sum (proven round 6): VALU-speed cross-lane, no LDS pipe.
// ---------------------------------------------------------------------------
template <int CTRL>
__device__ __forceinline__ float dpp_add(float s) {
  return s + __int_as_float(__builtin_amdgcn_update_dpp(
      0, __float_as_int(s), CTRL, 0xf, 0xf, true));
}
__device__ __forceinline__ float wave_sum(float s) {
  s = dpp_add<0x111>(s);   // row_shr:1
  s = dpp_add<0x112>(s);   // row_shr:2
  s = dpp_add<0x114>(s);   // row_shr:4
  s = dpp_add<0x118>(s);   // row_shr:8   -> lane15 of each row = row sum
  s = dpp_add<0x142>(s);   // row_bcast:15 -> lane31 = r0+r1, lane63 = r2+r3
  s = dpp_add<0x143>(s);   // row_bcast:31 -> lane63 = total
  return __int_as_float(__builtin_amdgcn_readlane(__float_as_int(s), 63));
}

// ---------------------------------------------------------------------------
// Recurrence v7 (unchanged from R8): W2/Wc/b1 in registers, DPP reductions,
// 1-step P prefetch; paste runs as extra blocks of this launch (blockIdx >=
// BATCH), overlapping the ~426 MB X-write stream with the latency-bound
// recurrence (proven free in R8: total-gemm 653->637 despite absorbing paste).
// ---------------------------------------------------------------------------
__global__ __launch_bounds__(64, 1) void recur_kernel(
    const float* __restrict__ P,    // [6400][HID]
    const float* __restrict__ W2,   // [NCLS][HID]
    const float* __restrict__ b2,   // [NCLS]
    const float* __restrict__ Wc,   // [HID+4]
    const float* __restrict__ bc,   // [1]
    const float* __restrict__ b1,   // [HID]
    const int*   __restrict__ idx,  // [B]
    float*       __restrict__ out,  // [B][NCLS]
    const float* __restrict__ inp,  // [B][D_IN][WIN]  (paste)
    float*       __restrict__ outX) // [B][D_IN][T]    (paste)
{
  int L = threadIdx.x;
  int b = blockIdx.x;

  if (b >= BATCH) {
    // ---- paste path: X = zeros with input window pasted at idx[b] ----
    int tid = (b - BATCH) * 64 + L;
    const int stride = RPASTE * 64;
    for (int i = tid; i < TOTQ; i += stride) {
      int q  = i % 75;
      int rd = i / 75;
      int bb = rd / D_IN;
      int d  = rd - bb * D_IN;
      int ib = idx[bb];
      const float* ip = inp + (size_t)bb * (D_IN * WIN) + (size_t)d * WIN;
      int t0 = q * 4;
      float v[4];
#pragma unroll
      for (int e = 0; e < 4; ++e) {
        unsigned w = (unsigned)(t0 + e - ib);
        v[e] = (w < (unsigned)WIN) ? ip[w] : 0.f;
      }
      *(float4*)&outX[(size_t)rd * TSTEPS + t0] = make_float4(v[0], v[1], v[2], v[3]);
    }
    return;
  }

  int myidx = idx[b];
  const float* Pb = P + (size_t)b * WIN * HID;

  float m[13], b1r[13], wcr[13];
  float w2r[NCLS][13];
  unsigned smask = 0;
#pragma unroll
  for (int rr = 0; rr < 13; ++rr) {
    int j = L + 64 * rr;
    bool ok = (j < HID);
    m[rr]   = 0.f;
    b1r[rr] = ok ? b1[j] : 0.f;
    wcr[rr] = ok ? Wc[j] : 0.f;
#pragma unroll
    for (int c = 0; c < NCLS; ++c)
      w2r[c][rr] = ok ? W2[c * HID + j] : 0.f;
  }

  float cm = 0.f, cs = 0.f, bgt = 1.f;
  float bc0 = bc[0];
  float wf0 = Wc[HID], wf1 = Wc[HID + 1], wf2 = Wc[HID + 2], wf3 = Wc[HID + 3];

  float h2m[10], h2s[10], sum2[10], b2r[10];
#pragma unroll
  for (int c = 0; c < NCLS; ++c) { h2m[c] = 0.f; h2s[c] = 0.f; sum2[c] = 0.f; b2r[c] = b2[c]; }

  // prefetch P row for step 0
  float cur[13];
  {
    unsigned w0 = (unsigned)(0 - myidx);
    if (w0 < (unsigned)WIN) {
      const float* Pr = Pb + (size_t)w0 * HID;
#pragma unroll
      for (int rr = 0; rr < 13; ++rr) {
        int j = L + 64 * rr;
        cur[rr] = (j < HID) ? Pr[j] : 0.f;
      }
    } else {
#pragma unroll
      for (int rr = 0; rr < 13; ++rr) cur[rr] = 0.f;
    }
  }

  for (int step = 0; step < TSTEPS; ++step) {
    float gate = (step == 0) ? 1.f : cs;

    // unconditional prefetch of next step's P row (independent of this
    // step's chain; gating is applied at use as *gate, exact for {0,1})
    float nxt[13];
    {
      unsigned wn = (unsigned)(step + 1 - myidx);
      if (wn < (unsigned)WIN) {
        const float* Pr = Pb + (size_t)wn * HID;
#pragma unroll
        for (int rr = 0; rr < 13; ++rr) {
          int j = L + 64 * rr;
          nxt[rr] = (j < HID) ? Pr[j] : 0.f;
        }
      } else {
#pragma unroll
        for (int rr = 0; rr < 13; ++rr) nxt[rr] = 0.f;
      }
    }

    unsigned nmask = 0;
#pragma unroll
    for (int rr = 0; rr < 13; ++rr) {
      float mprev = ((smask >> rr) & 1u) ? 0.f : m[rr] * 0.1f;
      float mv = mprev + cur[rr] * gate + b1r[rr];
      m[rr] = mv;
      nmask |= (mv > 0.5f) ? (1u << rr) : 0u;
    }
    smask = nmask;

    unsigned long long ball = __ballot(smask != 0u);

    float ctrl = 0.f;
    float dot[10];
#pragma unroll
    for (int c = 0; c < NCLS; ++c) dot[c] = 0.f;

    if (ball) {
      // ctrl dot: branchless FMA over own units, DPP wave reduce
      float cacc = 0.f;
#pragma unroll
      for (int rr = 0; rr < 13; ++rr) {
        float f = (float)((smask >> rr) & 1u);
        cacc = fmaf(f, wcr[rr], cacc);
      }
      ctrl = wave_sum(cacc);

      // h2 dots: per-lane partials over own 13 units (all-register), then
      // DPP wave reduce x10
#pragma unroll
      for (int rr = 0; rr < 13; ++rr) {
        float f = (float)((smask >> rr) & 1u);
#pragma unroll
        for (int c = 0; c < NCLS; ++c)
          dot[c] = fmaf(f, w2r[c][rr], dot[c]);
      }
#pragma unroll
      for (int c = 0; c < NCLS; ++c) dot[c] = wave_sum(dot[c]);
    }

    // ctrl neuron + budget (uses prev-step cs, then updates it)
    bgt += (cs == 1.f) ? 1.f : 0.f;
    float fq = wf0;
    if ((step & 1) == 0)   fq += wf1;
    if (step % 10 == 0)    fq += wf2;
    if (step % 100 == 0)   fq += wf3;
    float cv = (cs != 0.f ? 0.f : cm * 0.1f) + ctrl + fq + bc0;
    cm = cv;
    cs = (cv > 0.5f) ? 1.f : 0.f;

    // h2 membrane update every step (dot==0 on silent steps)
#pragma unroll
    for (int c = 0; c < NCLS; ++c) {
      float v = (h2s[c] != 0.f ? 0.f : h2m[c] * 0.1f) + dot[c] + b2r[c];
      h2m[c] = v;
      h2s[c] = (v > 0.5f) ? 1.f : 0.f;
      sum2[c] += h2s[c];
    }

#pragma unroll
    for (int rr = 0; rr < 13; ++rr) cur[rr] = nxt[rr];
  }

  if (L == 0) {
#pragma unroll
    for (int c = 0; c < NCLS; ++c) out[b * NCLS + c] = sum2[c] / bgt;
  }
}

// ---------------------------------------------------------------------------
extern "C" void kernel_launch(void* const* d_in, const int* in_sizes, int n_in,
                              void* d_out, int out_size, void* d_ws, size_t ws_size,
                              hipStream_t stream) {
  const float* inp = (const float*)d_in[0];
  const int*   idx = (const int*)d_in[2];
  const float* W1  = (const float*)d_in[3];
  const float* b1  = (const float*)d_in[4];
  const float* W2  = (const float*)d_in[5];
  const float* b2  = (const float*)d_in[6];
  const float* Wc  = (const float*)d_in[7];
  const float* bc  = (const float*)d_in[8];

  float* out = (float*)d_out;   // [0,1280): rate ; then X
  float* P   = (float*)d_ws;    // [6400][800] fp32 = 20.48 MB

  gemm_kernel<<<GEMM_BLOCKS, BLK, 0, stream>>>(inp, W1, P);

  recur_kernel<<<BATCH + RPASTE, 64, 0, stream>>>(
      P, W2, b2, Wc, bc, b1, idx, out, inp, out + BATCH * NCLS);
}